// Round 10
// baseline (306.519 us; speedup 1.0000x reference)
//
#include <hip/hip_runtime.h>
#include <cstdint>
#include <cstddef>

#define N_ 4096
#define C_ 256

typedef _Float16 h8 __attribute__((ext_vector_type(8)));
typedef _Float16 h4 __attribute__((ext_vector_type(4)));
typedef float f4 __attribute__((ext_vector_type(4)));

__device__ __forceinline__ void gl2lds16(const void* g, void* l) {
  __builtin_amdgcn_global_load_lds((const __attribute__((address_space(1))) void*)g,
                                   (__attribute__((address_space(3))) void*)l, 16, 0, 0);
}

// ---- branch-free exact top-16 primitives (f64 packed keys: key = (double)d2
// with the 12-bit source index OR'd into the low mantissa bits).
__device__ __forceinline__ void ce_asc(double& a, double& b) {
  double mn = fmin(a, b), mx = fmax(a, b);
  a = mn; b = mx;
}

// Batcher odd-even mergesort of 8, ascending: 19 CEs (vs bitonic 24).
// Construction: sort pairs; M(2,2) x2; M(4,4) = evens M(2,2) + odds M(2,2)
// + final (1,2)(3,4)(5,6). Layered for ILP.
__device__ __forceinline__ void sort8_asc(double* c) {
  ce_asc(c[0], c[1]); ce_asc(c[2], c[3]); ce_asc(c[4], c[5]); ce_asc(c[6], c[7]);
  ce_asc(c[0], c[2]); ce_asc(c[1], c[3]); ce_asc(c[4], c[6]); ce_asc(c[5], c[7]);
  ce_asc(c[1], c[2]); ce_asc(c[5], c[6]);
  ce_asc(c[0], c[4]); ce_asc(c[1], c[5]); ce_asc(c[2], c[6]); ce_asc(c[3], c[7]);
  ce_asc(c[2], c[4]); ce_asc(c[3], c[5]);
  ce_asc(c[1], c[2]); ce_asc(c[3], c[4]); ce_asc(c[5], c[6]);
}

// karr[0..15] asc; c[0..7] asc -> karr = 16 smallest of union, asc.
__device__ __forceinline__ void merge8_top16(double* karr, const double* c) {
#pragma unroll
  for (int i = 0; i < 8; i++)
    karr[8 + i] = fmin(karr[8 + i], c[7 - i]);
#pragma unroll
  for (int j = 8; j > 0; j >>= 1)
#pragma unroll
    for (int i = 0; i < 16; i++) {
      int l = i ^ j;
      if (l > i) ce_asc(karr[i], karr[l]);
    }
}

// merge two sorted-16 lists, keep 16 smallest.
__device__ __forceinline__ void merge16d(double* a, const double* b) {
#pragma unroll
  for (int i = 0; i < 16; i++) a[i] = fmin(a[i], b[15 - i]);
#pragma unroll
  for (int j = 8; j > 0; j >>= 1)
#pragma unroll
    for (int i = 0; i < 16; i++) {
      int l = i ^ j;
      if (l > i) {
        double mn = fmin(a[i], a[l]), mx = fmax(a[i], a[l]);
        a[i] = mn; a[l] = mx;
      }
    }
}

// -------------------------------------- sq = sum x^2 ; split x -> f16 hi + lo
__global__ __launch_bounds__(256) void k_prep(const float* __restrict__ x,
                                              float* __restrict__ sq,
                                              _Float16* __restrict__ xh,
                                              _Float16* __restrict__ xl) {
  int wave = threadIdx.x >> 6, lane = threadIdx.x & 63;
  int row = blockIdx.x * 4 + wave;            // 0..16383
  size_t off = (size_t)row * C_ + lane * 4;
  float4 v = *(const float4*)(x + off);
  h4 hi; hi[0] = (_Float16)v.x; hi[1] = (_Float16)v.y;
         hi[2] = (_Float16)v.z; hi[3] = (_Float16)v.w;
  h4 lo; lo[0] = (_Float16)(v.x - (float)hi[0]); lo[1] = (_Float16)(v.y - (float)hi[1]);
         lo[2] = (_Float16)(v.z - (float)hi[2]); lo[3] = (_Float16)(v.w - (float)hi[3]);
  *(h4*)(xh + off) = hi;
  *(h4*)(xl + off) = lo;
  float s = v.x * v.x + v.y * v.y + v.z * v.z + v.w * v.w;
  s += __shfl_xor(s, 32); s += __shfl_xor(s, 16); s += __shfl_xor(s, 8);
  s += __shfl_xor(s, 4);  s += __shfl_xor(s, 2);  s += __shfl_xor(s, 1);
  if (lane == 0) sq[row] = s;
}

// ------------------- split W into f16 hi/lo, transposed to B-frag row layout
__global__ __launch_bounds__(256) void k_wsplit(const float* __restrict__ Wq,
                                                const float* __restrict__ Wk,
                                                const float* __restrict__ Wv,
                                                _Float16* __restrict__ wh,
                                                _Float16* __restrict__ wl) {
  int g = blockIdx.x * 256 + threadIdx.x;     // 0..196607
  int m = g >> 16, e = g & 65535;
  int k = e >> 8, j = e & 255;
  const float* W = (m == 0) ? Wq : ((m == 1) ? Wk : Wv);
  float v = W[k * 256 + j];
  _Float16 hi = (_Float16)v;
  _Float16 lo = (_Float16)(v - (float)hi);
  wh[m * 65536 + j * 256 + k] = hi;
  wl[m * 65536 + j * 256 + k] = lo;
}

// --------------------------- q/k/v projections via split-f16 MFMA (3 passes)
// grid 768: m(3) x rb(128) x cp(2). q -> f32; k,v -> f16.
__global__ __launch_bounds__(256, 3) void k_proj(const _Float16* __restrict__ xh,
                                                 const _Float16* __restrict__ xl,
                                                 const _Float16* __restrict__ wh,
                                                 const _Float16* __restrict__ wl,
                                                 const float* __restrict__ bqp,
                                                 const float* __restrict__ bkp,
                                                 const float* __restrict__ bvp,
                                                 float* __restrict__ qf,
                                                 _Float16* __restrict__ kh,
                                                 _Float16* __restrict__ vh) {
  int tid = threadIdx.x;
  int bid = blockIdx.x;
  int m   = bid >> 8;
  int rb  = (bid >> 1) & 127;
  int cp  = bid & 1;
  int wave = tid >> 6, lane = tid & 63, quad = lane >> 4, l16 = lane & 15;
  const float* bb = (m == 0) ? bqp : ((m == 1) ? bkp : bvp);
  int row0 = rb * 128 + wave * 32;

  h8 Ah[2][8], Al[2][8];
#pragma unroll
  for (int rt = 0; rt < 2; rt++)
#pragma unroll
    for (int kc = 0; kc < 8; kc++) {
      size_t off = (size_t)(row0 + rt * 16 + l16) * C_ + kc * 32 + quad * 8;
      Ah[rt][kc] = *(const h8*)(xh + off);
      Al[rt][kc] = *(const h8*)(xl + off);
    }
  const _Float16* whm = wh + (size_t)m * 65536;
  const _Float16* wlm = wl + (size_t)m * 65536;

  f4 acc[2][8];
#pragma unroll
  for (int rt = 0; rt < 2; rt++)
#pragma unroll
    for (int ct = 0; ct < 8; ct++) acc[rt][ct] = f4{0.f, 0.f, 0.f, 0.f};
#pragma unroll
  for (int kc = 0; kc < 8; kc++) {
#pragma unroll
    for (int ct = 0; ct < 8; ct++) {
      int col = cp * 128 + ct * 16 + l16;
      h8 bh = *(const h8*)(whm + (size_t)col * 256 + kc * 32 + quad * 8);
      h8 bl = *(const h8*)(wlm + (size_t)col * 256 + kc * 32 + quad * 8);
#pragma unroll
      for (int rt = 0; rt < 2; rt++) {
        acc[rt][ct] = __builtin_amdgcn_mfma_f32_16x16x32_f16(Ah[rt][kc], bh, acc[rt][ct], 0, 0, 0);
        acc[rt][ct] = __builtin_amdgcn_mfma_f32_16x16x32_f16(Ah[rt][kc], bl, acc[rt][ct], 0, 0, 0);
        acc[rt][ct] = __builtin_amdgcn_mfma_f32_16x16x32_f16(Al[rt][kc], bh, acc[rt][ct], 0, 0, 0);
      }
    }
  }
  _Float16* d16 = (m == 1) ? kh : vh;
#pragma unroll
  for (int rt = 0; rt < 2; rt++)
#pragma unroll
    for (int ct = 0; ct < 8; ct++) {
      int col = cp * 128 + ct * 16 + l16;
      float bias = bb[col];
#pragma unroll
      for (int i = 0; i < 4; i++) {
        int r = row0 + rt * 16 + quad * 4 + i;
        float o = acc[rt][ct][i] + bias;
        if (m == 0) qf[(size_t)r * C_ + col] = o;
        else        d16[(size_t)r * C_ + col] = (_Float16)o;
      }
    }
}

// ---- split-f16 MFMA distance GEMM + f64 bitonic top-16.
// r1 dataflow exactly (128 targets x 1024 srcs, 32-src chunks, two barriers,
// glds staging, block-wide sc exchange) but 8 waves x 16 rows instead of
// 4 x 32: per-wave A-state halves (64 regs) -> fits (512,3) = 170-reg budget
// -> 4 waves/SIMD (vs 2). Selection: 512 threads x 8 cands/chunk = one
// sort8(19CE)+merge8 per thread (same 15 ops/cand as r1).
// bid = ((b*32 + tile)*4 + s4); grid 512 x 512 threads.
__global__ __launch_bounds__(512, 3) void k_knn(const _Float16* __restrict__ xh,
                                                const _Float16* __restrict__ xl,
                                                const float* __restrict__ sq,
                                                double* __restrict__ pd) {
  __shared__ __align__(16) _Float16 Bh[16 * 528]; // 16 segs x (2 rows x 256 + pad)
  __shared__ __align__(16) _Float16 Bl[16 * 528];
  __shared__ __align__(16) float sc[128 * 36];    // row-major d2, stride 36
  __shared__ float sqS[32];

  int tid = threadIdx.x;
  int wave = tid >> 6, lane = tid & 63, quad = lane >> 4, l16 = lane & 15;
  int bid = blockIdx.x;
  int s4 = bid & 3, tile = (bid >> 2) & 31, b = bid >> 7;
  int bN = b * N_, n0 = tile * 128, src0g = s4 * 1024;

  // A-frags: wave's 16 target rows, full K, hi+lo, resident (~64 regs)
  h8 Ah[8], Al[8];
  int tb = bN + n0 + wave * 16;
#pragma unroll
  for (int kc = 0; kc < 8; kc++) {
    size_t off = (size_t)(tb + l16) * C_ + kc * 32 + quad * 8;
    Ah[kc] = *(const h8*)(xh + off);
    Al[kc] = *(const h8*)(xl + off);
  }
  float sqT[4];
#pragma unroll
  for (int i = 0; i < 4; i++)
    sqT[i] = sq[tb + quad * 4 + i];

  double karr[16];
#pragma unroll
  for (int p = 0; p < 16; p++) karr[p] = 1e300;
  int rown = tid & 127;            // owned row for selection stream
  int part = tid >> 7;             // candidate quarter (8 cands each)

  // prologue: stage chunk 0. seg = 2 src rows = 1KB; 2 segs/wave.
  {
    const _Float16* gh = xh + (size_t)(bN + src0g) * C_ + lane * 8;
    const _Float16* gl = xl + (size_t)(bN + src0g) * C_ + lane * 8;
#pragma unroll
    for (int k = 0; k < 2; k++) {
      int seg = wave * 2 + k;
      gl2lds16(gh + seg * 512, &Bh[seg * 528]);
      gl2lds16(gl + seg * 512, &Bl[seg * 528]);
    }
    if (tid < 32) sqS[tid] = sq[bN + src0g + tid];
  }

  int hb0 = ((l16 >> 1) * 528) + ((l16 & 1) * 256) + quad * 8;          // ct=0 row
  int hb1 = (((16 + l16) >> 1) * 528) + ((l16 & 1) * 256) + quad * 8;   // ct=1 row

#pragma unroll 1
  for (int ch = 0; ch < 32; ch++) {
    int src0 = src0g + ch * 32;
    __syncthreads();                       // staged B(ch) + sqS(ch) visible

    f4 acc[2];
    acc[0] = f4{0.f, 0.f, 0.f, 0.f};
    acc[1] = f4{0.f, 0.f, 0.f, 0.f};
#pragma unroll
    for (int kc = 0; kc < 8; kc++) {
      h8 bh0 = *(const h8*)(&Bh[hb0 + kc * 32]);
      h8 bh1 = *(const h8*)(&Bh[hb1 + kc * 32]);
      h8 bl0 = *(const h8*)(&Bl[hb0 + kc * 32]);
      h8 bl1 = *(const h8*)(&Bl[hb1 + kc * 32]);
      acc[0] = __builtin_amdgcn_mfma_f32_16x16x32_f16(Ah[kc], bh0, acc[0], 0, 0, 0);
      acc[1] = __builtin_amdgcn_mfma_f32_16x16x32_f16(Ah[kc], bh1, acc[1], 0, 0, 0);
      acc[0] = __builtin_amdgcn_mfma_f32_16x16x32_f16(Ah[kc], bl0, acc[0], 0, 0, 0);
      acc[1] = __builtin_amdgcn_mfma_f32_16x16x32_f16(Ah[kc], bl1, acc[1], 0, 0, 0);
      acc[0] = __builtin_amdgcn_mfma_f32_16x16x32_f16(Al[kc], bh0, acc[0], 0, 0, 0);
      acc[1] = __builtin_amdgcn_mfma_f32_16x16x32_f16(Al[kc], bh1, acc[1], 0, 0, 0);
    }
    // d2 -> sc row-major (stride 36), self-masked
    float sqSr[2] = {sqS[l16], sqS[16 + l16]};
#pragma unroll
    for (int ct = 0; ct < 2; ct++) {
      int c = ct * 16 + l16;
#pragma unroll
      for (int i = 0; i < 4; i++) {
        int r = wave * 16 + quad * 4 + i;
        float d2 = sqT[i] + sqSr[ct] - 2.0f * acc[ct][i];
        if (n0 + r == src0 + c) d2 = 1e38f;
        sc[r * 36 + c] = d2;
      }
    }
    __syncthreads();                       // sc ready; all B(ch) reads done

    if (ch < 31) {                         // async-stage chunk ch+1
      int srcn = src0 + 32;
      const _Float16* gh = xh + (size_t)(bN + srcn) * C_ + lane * 8;
      const _Float16* gl = xl + (size_t)(bN + srcn) * C_ + lane * 8;
#pragma unroll
      for (int k = 0; k < 2; k++) {
        int seg = wave * 2 + k;
        gl2lds16(gh + seg * 512, &Bh[seg * 528]);
        gl2lds16(gl + seg * 512, &Bl[seg * 528]);
      }
      if (tid < 32) sqS[tid] = sq[bN + srcn + tid];
    }

    // merge: 8 candidates (my quarter-row): pack -> sort8 -> merge-top16.
    float dv[8];
#pragma unroll
    for (int k4 = 0; k4 < 2; k4++)
      *(float4*)&dv[k4 * 4] = *(const float4*)(&sc[rown * 36 + part * 8 + k4 * 4]);
    double c8[8];
#pragma unroll
    for (int j = 0; j < 8; j++) {
      double key = (double)dv[j];
      c8[j] = __longlong_as_double(__double_as_longlong(key) |
                                   (unsigned)(src0 + part * 8 + j));
    }
    sort8_asc(c8);
    merge8_top16(karr, c8);
  }

  // epilogue: combine the 4 part-streams per row through sc (stride 17 f64).
  __syncthreads();
  double* ex = (double*)sc;              // 128 x 17 f64 = 17,408 B <= 18,432
  if (part == 3) {
#pragma unroll
    for (int p = 0; p < 16; p++) ex[rown * 17 + p] = karr[p];
  }
  __syncthreads();
  if (part == 2) {
    double other[16];
#pragma unroll
    for (int p = 0; p < 16; p++) other[p] = ex[rown * 17 + p];
    merge16d(karr, other);
  }
  __syncthreads();
  if (part == 1) {
#pragma unroll
    for (int p = 0; p < 16; p++) ex[rown * 17 + p] = karr[p];
  }
  __syncthreads();
  if (part == 0) {
    double other[16];
#pragma unroll
    for (int p = 0; p < 16; p++) other[p] = ex[rown * 17 + p];
    merge16d(karr, other);
  }
  __syncthreads();
  if (part == 2) {
#pragma unroll
    for (int p = 0; p < 16; p++) ex[rown * 17 + p] = karr[p];
  }
  __syncthreads();
  if (part == 0) {
    double other[16];
#pragma unroll
    for (int p = 0; p < 16; p++) other[p] = ex[rown * 17 + p];
    merge16d(karr, other);
#pragma unroll
    for (int p = 0; p < 16; p++)
      pd[((size_t)bid * 128 + rown) * 16 + p] = karr[p];
  }
}

// --------------------- merge 4 partial sorted packed lists -> top-16 indices
// branch-free register tree merge; grid 256 x 64.
__global__ __launch_bounds__(64) void k_kmerge(const double* __restrict__ pd,
                                               int* __restrict__ idxo) {
  int g = blockIdx.x * 64 + threadIdx.x;       // 0..16383
  int b = g >> 12, n = g & 4095;
  int tile = n >> 7, r = n & 127;
  size_t base = (size_t)(((b * 32 + tile) * 4) * 128 + r) * 16;

  double acc[16], other[16];
#pragma unroll
  for (int p = 0; p < 16; p++) acc[p] = pd[base + p];
#pragma unroll
  for (int s = 1; s < 4; s++) {
    size_t bs = base + (size_t)s * 128 * 16;
#pragma unroll
    for (int p = 0; p < 16; p++) other[p] = pd[bs + p];
    merge16d(acc, other);
  }
#pragma unroll
  for (int k = 0; k < 16; k++)
    idxo[(size_t)g * 16 + k] = (int)(__double_as_longlong(acc[k]) & 0xFFF);
}

// -------------------------------------------- gather + attention (wave/node)
// k/v gathered as f16 (half the bytes; batch working set fits XCD L2).
__global__ __launch_bounds__(256) void k_attn(const float* __restrict__ qf,
                                              const _Float16* __restrict__ kh,
                                              const _Float16* __restrict__ vh,
                                              const int* __restrict__ idxv,
                                              float* __restrict__ out) {
  int wave = threadIdx.x >> 6, lane = threadIdx.x & 63;
  int g = blockIdx.x * 4 + wave;               // node 0..16383
  int bN = (g >> 12) << 12;
  float4 q4 = *(const float4*)(qf + (size_t)g * C_ + lane * 4);
  int my = idxv[(size_t)g * 16 + (lane & 15)];
  const float scale = 0.17677669529663687f;    // 1/sqrt(32)

  float s[16];
  h4 vv[16];
#pragma unroll
  for (int j = 0; j < 16; j++) {
    int nb = __shfl(my, j);
    size_t base = (size_t)(bN + nb) * C_ + lane * 4;
    h4 k4 = *(const h4*)(kh + base);
    vv[j] = *(const h4*)(vh + base);
    float p = (float)k4[0] * q4.x + (float)k4[1] * q4.y +
              (float)k4[2] * q4.z + (float)k4[3] * q4.w;
    p += __shfl_xor(p, 1); p += __shfl_xor(p, 2); p += __shfl_xor(p, 4);
    s[j] = p * scale;
  }
  float mx = s[0];
#pragma unroll
  for (int j = 1; j < 16; j++) mx = fmaxf(mx, s[j]);
  float den = 0.f;
#pragma unroll
  for (int j = 0; j < 16; j++) { s[j] = __expf(s[j] - mx); den += s[j]; }
  float inv = 1.0f / den;
  float4 o; o.x = 0.f; o.y = 0.f; o.z = 0.f; o.w = 0.f;
#pragma unroll
  for (int j = 0; j < 16; j++) {
    float w = s[j] * inv;
    o.x = fmaf(w, (float)vv[j][0], o.x); o.y = fmaf(w, (float)vv[j][1], o.y);
    o.z = fmaf(w, (float)vv[j][2], o.z); o.w = fmaf(w, (float)vv[j][3], o.w);
  }
  *(float4*)(out + (size_t)g * C_ + lane * 4) = o;
}

extern "C" void kernel_launch(void* const* d_in, const int* in_sizes, int n_in,
                              void* d_out, int out_size, void* d_ws, size_t ws_size,
                              hipStream_t stream) {
  const float* x  = (const float*)d_in[0];
  const float* Wq = (const float*)d_in[1];
  const float* bq = (const float*)d_in[2];
  const float* Wk = (const float*)d_in[3];
  const float* bk = (const float*)d_in[4];
  const float* Wv = (const float*)d_in[5];
  const float* bv = (const float*)d_in[6];
  float* out = (float*)d_out;

  char* ws = (char*)d_ws;
  float*     sqp  = (float*)(ws + 0);                //  64 KB
  _Float16*  xh   = (_Float16*)(ws + 65536);         //   8 MB
  _Float16*  xl   = (_Float16*)(ws + 8454144);       //   8 MB
  float*     qf   = (float*)(ws + 16842752);         //  16 MB
  _Float16*  khp  = (_Float16*)(ws + 33619968);      //   8 MB
  _Float16*  vhp  = (_Float16*)(ws + 50397184);      //   8 MB
  double*    pd   = (double*)(ws + 67174400);        //   8 MB
  int*       idxb = (int*)  (ws + 75563008);         //   1 MB
  _Float16*  whf  = (_Float16*)(ws + 76611584);      // 384 KB
  _Float16*  wlf  = (_Float16*)(ws + 77004800);      // 384 KB (total ~74 MB)

  k_prep  <<<4096, 256, 0, stream>>>(x, sqp, xh, xl);
  k_wsplit<<<768,  256, 0, stream>>>(Wq, Wk, Wv, whf, wlf);
  k_proj  <<<768,  256, 0, stream>>>(xh, xl, whf, wlf, bq, bk, bv, qf, khp, vhp);
  k_knn   <<<512,  512, 0, stream>>>(xh, xl, sqp, pd);
  k_kmerge<<<256,  64,  0, stream>>>(pd, idxb);
  k_attn  <<<4096, 256, 0, stream>>>(qf, khp, vhp, idxb, out);
}

// Round 11
// 281.769 us; speedup vs baseline: 1.0878x; 1.0878x over previous
//
#include <hip/hip_runtime.h>
#include <cstdint>
#include <cstddef>

#define N_ 4096
#define C_ 256

typedef _Float16 h8 __attribute__((ext_vector_type(8)));
typedef _Float16 h4 __attribute__((ext_vector_type(4)));
typedef float f4 __attribute__((ext_vector_type(4)));

__device__ __forceinline__ void gl2lds16(const void* g, void* l) {
  __builtin_amdgcn_global_load_lds((const __attribute__((address_space(1))) void*)g,
                                   (__attribute__((address_space(3))) void*)l, 16, 0, 0);
}

// ---- branch-free exact top-16 primitives (f64 packed keys: key = (double)d2
// with the 12-bit source index OR'd into the low mantissa bits).
__device__ __forceinline__ void ce_asc(double& a, double& b) {
  double mn = fmin(a, b), mx = fmax(a, b);
  a = mn; b = mx;
}

// Batcher odd-even mergesort of 8, ascending: 19 CEs (vs bitonic 24).
// Field-verified in the r10 passing run.
__device__ __forceinline__ void sort8_asc(double* c) {
  ce_asc(c[0], c[1]); ce_asc(c[2], c[3]); ce_asc(c[4], c[5]); ce_asc(c[6], c[7]);
  ce_asc(c[0], c[2]); ce_asc(c[1], c[3]); ce_asc(c[4], c[6]); ce_asc(c[5], c[7]);
  ce_asc(c[1], c[2]); ce_asc(c[5], c[6]);
  ce_asc(c[0], c[4]); ce_asc(c[1], c[5]); ce_asc(c[2], c[6]); ce_asc(c[3], c[7]);
  ce_asc(c[2], c[4]); ce_asc(c[3], c[5]);
  ce_asc(c[1], c[2]); ce_asc(c[3], c[4]); ce_asc(c[5], c[6]);
}

// karr[0..15] asc; c[0..7] asc -> karr = 16 smallest of union, asc.
__device__ __forceinline__ void merge8_top16(double* karr, const double* c) {
#pragma unroll
  for (int i = 0; i < 8; i++)
    karr[8 + i] = fmin(karr[8 + i], c[7 - i]);
#pragma unroll
  for (int j = 8; j > 0; j >>= 1)
#pragma unroll
    for (int i = 0; i < 16; i++) {
      int l = i ^ j;
      if (l > i) ce_asc(karr[i], karr[l]);
    }
}

// ---------------- fused: sq/hi-lo split of x (blocks 0..4095) + W split
// (blocks 4096..4863). Independent inputs; one dispatch instead of two.
__global__ __launch_bounds__(256) void k_pre(const float* __restrict__ x,
                                             float* __restrict__ sq,
                                             _Float16* __restrict__ xh,
                                             _Float16* __restrict__ xl,
                                             const float* __restrict__ Wq,
                                             const float* __restrict__ Wk,
                                             const float* __restrict__ Wv,
                                             _Float16* __restrict__ wh,
                                             _Float16* __restrict__ wl) {
  int bid = blockIdx.x;
  if (bid < 4096) {
    int wave = threadIdx.x >> 6, lane = threadIdx.x & 63;
    int row = bid * 4 + wave;                 // 0..16383
    size_t off = (size_t)row * C_ + lane * 4;
    float4 v = *(const float4*)(x + off);
    h4 hi; hi[0] = (_Float16)v.x; hi[1] = (_Float16)v.y;
           hi[2] = (_Float16)v.z; hi[3] = (_Float16)v.w;
    h4 lo; lo[0] = (_Float16)(v.x - (float)hi[0]); lo[1] = (_Float16)(v.y - (float)hi[1]);
           lo[2] = (_Float16)(v.z - (float)hi[2]); lo[3] = (_Float16)(v.w - (float)hi[3]);
    *(h4*)(xh + off) = hi;
    *(h4*)(xl + off) = lo;
    float s = v.x * v.x + v.y * v.y + v.z * v.z + v.w * v.w;
    s += __shfl_xor(s, 32); s += __shfl_xor(s, 16); s += __shfl_xor(s, 8);
    s += __shfl_xor(s, 4);  s += __shfl_xor(s, 2);  s += __shfl_xor(s, 1);
    if (lane == 0) sq[row] = s;
  } else {
    int g = (bid - 4096) * 256 + threadIdx.x; // 0..196607
    int m = g >> 16, e = g & 65535;
    int k = e >> 8, j = e & 255;
    const float* W = (m == 0) ? Wq : ((m == 1) ? Wk : Wv);
    float v = W[k * 256 + j];
    _Float16 hi = (_Float16)v;
    _Float16 lo = (_Float16)(v - (float)hi);
    wh[m * 65536 + j * 256 + k] = hi;
    wl[m * 65536 + j * 256 + k] = lo;
  }
}

// --------------------------- q/k/v projections via split-f16 MFMA (3 passes)
// grid 768: m(3) x rb(128) x cp(2). q -> f32; k,v -> f16.
__global__ __launch_bounds__(256, 3) void k_proj(const _Float16* __restrict__ xh,
                                                 const _Float16* __restrict__ xl,
                                                 const _Float16* __restrict__ wh,
                                                 const _Float16* __restrict__ wl,
                                                 const float* __restrict__ bqp,
                                                 const float* __restrict__ bkp,
                                                 const float* __restrict__ bvp,
                                                 float* __restrict__ qf,
                                                 _Float16* __restrict__ kh,
                                                 _Float16* __restrict__ vh) {
  int tid = threadIdx.x;
  int bid = blockIdx.x;
  int m   = bid >> 8;
  int rb  = (bid >> 1) & 127;
  int cp  = bid & 1;
  int wave = tid >> 6, lane = tid & 63, quad = lane >> 4, l16 = lane & 15;
  const float* bb = (m == 0) ? bqp : ((m == 1) ? bkp : bvp);
  int row0 = rb * 128 + wave * 32;

  h8 Ah[2][8], Al[2][8];
#pragma unroll
  for (int rt = 0; rt < 2; rt++)
#pragma unroll
    for (int kc = 0; kc < 8; kc++) {
      size_t off = (size_t)(row0 + rt * 16 + l16) * C_ + kc * 32 + quad * 8;
      Ah[rt][kc] = *(const h8*)(xh + off);
      Al[rt][kc] = *(const h8*)(xl + off);
    }
  const _Float16* whm = wh + (size_t)m * 65536;
  const _Float16* wlm = wl + (size_t)m * 65536;

  f4 acc[2][8];
#pragma unroll
  for (int rt = 0; rt < 2; rt++)
#pragma unroll
    for (int ct = 0; ct < 8; ct++) acc[rt][ct] = f4{0.f, 0.f, 0.f, 0.f};
#pragma unroll
  for (int kc = 0; kc < 8; kc++) {
#pragma unroll
    for (int ct = 0; ct < 8; ct++) {
      int col = cp * 128 + ct * 16 + l16;
      h8 bh = *(const h8*)(whm + (size_t)col * 256 + kc * 32 + quad * 8);
      h8 bl = *(const h8*)(wlm + (size_t)col * 256 + kc * 32 + quad * 8);
#pragma unroll
      for (int rt = 0; rt < 2; rt++) {
        acc[rt][ct] = __builtin_amdgcn_mfma_f32_16x16x32_f16(Ah[rt][kc], bh, acc[rt][ct], 0, 0, 0);
        acc[rt][ct] = __builtin_amdgcn_mfma_f32_16x16x32_f16(Ah[rt][kc], bl, acc[rt][ct], 0, 0, 0);
        acc[rt][ct] = __builtin_amdgcn_mfma_f32_16x16x32_f16(Al[rt][kc], bh, acc[rt][ct], 0, 0, 0);
      }
    }
  }
  _Float16* d16 = (m == 1) ? kh : vh;
#pragma unroll
  for (int rt = 0; rt < 2; rt++)
#pragma unroll
    for (int ct = 0; ct < 8; ct++) {
      int col = cp * 128 + ct * 16 + l16;
      float bias = bb[col];
#pragma unroll
      for (int i = 0; i < 4; i++) {
        int r = row0 + rt * 16 + quad * 4 + i;
        float o = acc[rt][ct][i] + bias;
        if (m == 0) qf[(size_t)r * C_ + col] = o;
        else        d16[(size_t)r * C_ + col] = (_Float16)o;
      }
    }
}

// ---- split-f16 MFMA distance GEMM + branch-free packed-f64 top-16
// (the converged r1/r9 body). block: 128 targets x 1024 srcs (32-chunks),
// 4 waves, glds staging. bid = ((b*32 + tile)*4 + s4); grid 512 x 256.
__global__ __launch_bounds__(256, 2) void k_knn(const _Float16* __restrict__ xh,
                                                const _Float16* __restrict__ xl,
                                                const float* __restrict__ sq,
                                                double* __restrict__ pd) {
  __shared__ __align__(16) _Float16 Bh[16 * 528]; // 16 segs x (2 rows x 256 + pad)
  __shared__ __align__(16) _Float16 Bl[16 * 528];
  __shared__ __align__(16) float sc[128 * 36];    // row-major d2, stride 36
  __shared__ float sqS[32];

  int tid = threadIdx.x;
  int wave = tid >> 6, lane = tid & 63, quad = lane >> 4, l16 = lane & 15;
  int bid = blockIdx.x;
  int s4 = bid & 3, tile = (bid >> 2) & 31, b = bid >> 7;
  int bN = b * N_, n0 = tile * 128, src0g = s4 * 1024;

  h8 Ah[2][8], Al[2][8];
  int tb = bN + n0 + wave * 32;
#pragma unroll
  for (int rt = 0; rt < 2; rt++)
#pragma unroll
    for (int kc = 0; kc < 8; kc++) {
      size_t off = (size_t)(tb + rt * 16 + l16) * C_ + kc * 32 + quad * 8;
      Ah[rt][kc] = *(const h8*)(xh + off);
      Al[rt][kc] = *(const h8*)(xl + off);
    }
  float sqT[2][4];
#pragma unroll
  for (int rt = 0; rt < 2; rt++)
#pragma unroll
    for (int i = 0; i < 4; i++)
      sqT[rt][i] = sq[tb + rt * 16 + quad * 4 + i];

  double karr[16];
#pragma unroll
  for (int p = 0; p < 16; p++) karr[p] = 1e300;
  int rowo = tid & 127, half = tid >> 7;

  {
    const _Float16* gh = xh + (size_t)(bN + src0g) * C_ + lane * 8;
    const _Float16* gl = xl + (size_t)(bN + src0g) * C_ + lane * 8;
#pragma unroll
    for (int k = 0; k < 4; k++) {
      int seg = wave * 4 + k;
      gl2lds16(gh + seg * 512, &Bh[seg * 528]);
      gl2lds16(gl + seg * 512, &Bl[seg * 528]);
    }
    if (tid < 32) sqS[tid] = sq[bN + src0g + tid];
  }

  int hb0 = ((l16 >> 1) * 528) + ((l16 & 1) * 256) + quad * 8;
  int hb1 = (((16 + l16) >> 1) * 528) + ((l16 & 1) * 256) + quad * 8;

#pragma unroll 1
  for (int ch = 0; ch < 32; ch++) {
    int src0 = src0g + ch * 32;
    __syncthreads();

    f4 acc[2][2];
#pragma unroll
    for (int rt = 0; rt < 2; rt++)
#pragma unroll
      for (int ct = 0; ct < 2; ct++) acc[rt][ct] = f4{0.f, 0.f, 0.f, 0.f};
#pragma unroll
    for (int kc = 0; kc < 8; kc++) {
      h8 bh0 = *(const h8*)(&Bh[hb0 + kc * 32]);
      h8 bh1 = *(const h8*)(&Bh[hb1 + kc * 32]);
      h8 bl0 = *(const h8*)(&Bl[hb0 + kc * 32]);
      h8 bl1 = *(const h8*)(&Bl[hb1 + kc * 32]);
#pragma unroll
      for (int rt = 0; rt < 2; rt++) {
        acc[rt][0] = __builtin_amdgcn_mfma_f32_16x16x32_f16(Ah[rt][kc], bh0, acc[rt][0], 0, 0, 0);
        acc[rt][0] = __builtin_amdgcn_mfma_f32_16x16x32_f16(Ah[rt][kc], bl0, acc[rt][0], 0, 0, 0);
        acc[rt][0] = __builtin_amdgcn_mfma_f32_16x16x32_f16(Al[rt][kc], bh0, acc[rt][0], 0, 0, 0);
        acc[rt][1] = __builtin_amdgcn_mfma_f32_16x16x32_f16(Ah[rt][kc], bh1, acc[rt][1], 0, 0, 0);
        acc[rt][1] = __builtin_amdgcn_mfma_f32_16x16x32_f16(Ah[rt][kc], bl1, acc[rt][1], 0, 0, 0);
        acc[rt][1] = __builtin_amdgcn_mfma_f32_16x16x32_f16(Al[rt][kc], bh1, acc[rt][1], 0, 0, 0);
      }
    }
    float sqSr[2] = {sqS[l16], sqS[16 + l16]};
#pragma unroll
    for (int rt = 0; rt < 2; rt++)
#pragma unroll
      for (int ct = 0; ct < 2; ct++) {
        int c = ct * 16 + l16;
#pragma unroll
        for (int i = 0; i < 4; i++) {
          int r = wave * 32 + rt * 16 + quad * 4 + i;
          float d2 = sqT[rt][i] + sqSr[ct] - 2.0f * acc[rt][ct][i];
          if (n0 + r == src0 + c) d2 = 1e38f;
          sc[r * 36 + c] = d2;
        }
      }
    __syncthreads();

    if (ch < 31) {
      int srcn = src0 + 32;
      const _Float16* gh = xh + (size_t)(bN + srcn) * C_ + lane * 8;
      const _Float16* gl = xl + (size_t)(bN + srcn) * C_ + lane * 8;
#pragma unroll
      for (int k = 0; k < 4; k++) {
        int seg = wave * 4 + k;
        gl2lds16(gh + seg * 512, &Bh[seg * 528]);
        gl2lds16(gl + seg * 512, &Bl[seg * 528]);
      }
      if (tid < 32) sqS[tid] = sq[bN + srcn + tid];
    }

#pragma unroll
    for (int bt = 0; bt < 2; bt++) {
      float dv[8];
#pragma unroll
      for (int k4 = 0; k4 < 2; k4++)
        *(float4*)&dv[k4 * 4] = *(const float4*)(&sc[rowo * 36 + half * 16 + bt * 8 + k4 * 4]);
      double c8[8];
#pragma unroll
      for (int j = 0; j < 8; j++) {
        double key = (double)dv[j];
        c8[j] = __longlong_as_double(__double_as_longlong(key) |
                                     (unsigned)(src0 + half * 16 + bt * 8 + j));
      }
      sort8_asc(c8);
      merge8_top16(karr, c8);
    }
  }

  __syncthreads();
  double* scd = (double*)sc;
  if (tid >= 128) {
#pragma unroll
    for (int p = 0; p < 16; p++) scd[(tid - 128) * 17 + p] = karr[p];
  }
  __syncthreads();
  if (tid < 128) {
#pragma unroll
    for (int i = 0; i < 16; i++)
      karr[i] = fmin(karr[i], scd[tid * 17 + (15 - i)]);
#pragma unroll
    for (int j = 8; j > 0; j >>= 1)
#pragma unroll
      for (int i = 0; i < 16; i++) {
        int l = i ^ j;
        if (l > i) ce_asc(karr[i], karr[l]);
      }
#pragma unroll
    for (int p = 0; p < 16; p++)
      pd[((size_t)bid * 128 + tid) * 16 + p] = karr[p];
  }
}

// -------------------- gather + attention (wave/node), with the 4-way sorted
// list merge inlined as a distributed bitonic merge on lanes (el = lane&15;
// all four 16-lane groups redundantly compute the same merge — free on SIMD).
// Output is the top-16 SET; softmax + weighted sum are permutation-invariant.
__global__ __launch_bounds__(256) void k_attn(const float* __restrict__ qf,
                                              const _Float16* __restrict__ kh,
                                              const _Float16* __restrict__ vh,
                                              const double* __restrict__ pd,
                                              float* __restrict__ out) {
  int wave = threadIdx.x >> 6, lane = threadIdx.x & 63;
  int g = blockIdx.x * 4 + wave;               // node 0..16383
  int bN = (g >> 12) << 12;
  int el = lane & 15;

  // merge 4 sorted-16 packed lists from pd -> this lane's element of top-16
  int b = g >> 12, n = g & 4095;
  int tile = n >> 7, r = n & 127;
  size_t pbase = (size_t)(((b * 32 + tile) * 4) * 128 + r) * 16;
  double a = pd[pbase + el];
#pragma unroll
  for (int s = 1; s < 4; s++) {
    double bb = pd[pbase + (size_t)s * 128 * 16 + el];
    double br = __shfl(bb, (lane & ~15) | (15 - el));
    a = fmin(a, br);
#pragma unroll
    for (int j = 8; j > 0; j >>= 1) {
      double o = __shfl(a, lane ^ j);
      a = (el & j) ? fmax(a, o) : fmin(a, o);
    }
  }
  int my = (int)(__double_as_longlong(a) & 0xFFF);

  float4 q4 = *(const float4*)(qf + (size_t)g * C_ + lane * 4);
  const float scale = 0.17677669529663687f;    // 1/sqrt(32)

  float s[16];
  h4 vv[16];
#pragma unroll
  for (int j = 0; j < 16; j++) {
    int nb = __shfl(my, j);
    size_t base = (size_t)(bN + nb) * C_ + lane * 4;
    h4 k4 = *(const h4*)(kh + base);
    vv[j] = *(const h4*)(vh + base);
    float p = (float)k4[0] * q4.x + (float)k4[1] * q4.y +
              (float)k4[2] * q4.z + (float)k4[3] * q4.w;
    p += __shfl_xor(p, 1); p += __shfl_xor(p, 2); p += __shfl_xor(p, 4);
    s[j] = p * scale;
  }
  float mx = s[0];
#pragma unroll
  for (int j = 1; j < 16; j++) mx = fmaxf(mx, s[j]);
  float den = 0.f;
#pragma unroll
  for (int j = 0; j < 16; j++) { s[j] = __expf(s[j] - mx); den += s[j]; }
  float inv = 1.0f / den;
  float4 o; o.x = 0.f; o.y = 0.f; o.z = 0.f; o.w = 0.f;
#pragma unroll
  for (int j = 0; j < 16; j++) {
    float w = s[j] * inv;
    o.x = fmaf(w, (float)vv[j][0], o.x); o.y = fmaf(w, (float)vv[j][1], o.y);
    o.z = fmaf(w, (float)vv[j][2], o.z); o.w = fmaf(w, (float)vv[j][3], o.w);
  }
  *(float4*)(out + (size_t)g * C_ + lane * 4) = o;
}

extern "C" void kernel_launch(void* const* d_in, const int* in_sizes, int n_in,
                              void* d_out, int out_size, void* d_ws, size_t ws_size,
                              hipStream_t stream) {
  const float* x  = (const float*)d_in[0];
  const float* Wq = (const float*)d_in[1];
  const float* bq = (const float*)d_in[2];
  const float* Wk = (const float*)d_in[3];
  const float* bk = (const float*)d_in[4];
  const float* Wv = (const float*)d_in[5];
  const float* bv = (const float*)d_in[6];
  float* out = (float*)d_out;

  char* ws = (char*)d_ws;
  float*     sqp  = (float*)(ws + 0);                //  64 KB
  _Float16*  xh   = (_Float16*)(ws + 65536);         //   8 MB
  _Float16*  xl   = (_Float16*)(ws + 8454144);       //   8 MB
  float*     qf   = (float*)(ws + 16842752);         //  16 MB
  _Float16*  khp  = (_Float16*)(ws + 33619968);      //   8 MB
  _Float16*  vhp  = (_Float16*)(ws + 50397184);      //   8 MB
  double*    pd   = (double*)(ws + 67174400);        //   8 MB
  _Float16*  whf  = (_Float16*)(ws + 76611584);      // 384 KB
  _Float16*  wlf  = (_Float16*)(ws + 77004800);      // 384 KB (total ~74 MB)

  k_pre   <<<4864, 256, 0, stream>>>(x, sqp, xh, xl, Wq, Wk, Wv, whf, wlf);
  k_proj  <<<768,  256, 0, stream>>>(xh, xl, whf, wlf, bq, bk, bv, qf, khp, vhp);
  k_knn   <<<512,  256, 0, stream>>>(xh, xl, sqp, pd);
  k_attn  <<<4096, 256, 0, stream>>>(qf, khp, vhp, pd, out);
}